// Round 8
// baseline (309.917 us; speedup 1.0000x reference)
//
#include <hip/hip_runtime.h>
#include <stdint.h>

// Sparse strided conv: scatter (features@W1 -> grid) + gather (grid@W2 -> out).
// R8: scatter D-transposed (operand-swapped MFMA): D = [channel][voxel] so each
//     lane owns 4 consecutive channels of one voxel -> lane-local pk-bf16 pack,
//     ZERO shfls (was 864/wave), 16 atomic instrs/kv (was 32), per-lane row-id
//     predicate. Plus kv-split x2 (blockIdx.y) -> 7504 waves = 92% occupancy
//     (was 3752 = 46% cap, measured 35%).

#define N_VOX 120000
#define IC 32
#define OC 64
#define NKV 27
#define DZ 21
#define HY 200
#define WX 176
#define TBL_BITS 20
#define TBL_SIZE (1 << TBL_BITS)
#define TBL_MASK (TBL_SIZE - 1)
#define MAXROWS 480000

// ws layout (bytes)
#define OFF_KEYS 0                 // 4 MB
#define OFF_VALS 4194304           // 4 MB
#define OFF_CNT 8388608            // 256 B
#define OFF_ROWS 8388864           // 27*120000*4 = 12,960,000
#define OFF_FEATB 21348864         // 120000*32*2 = 7,680,000
#define OFF_W2T 29028864           // 27*32*64*2 = 110,592
#define OFF_W1T 29139456           // 27*64*32*2 = 110,592
#define OFF_GRID 29250048          // MAXROWS*64*2 = 61,440,000
#define WS_NEEDED (OFF_GRID + (size_t)MAXROWS * OC * 2)

typedef __attribute__((ext_vector_type(8))) short short8;
typedef __attribute__((ext_vector_type(4))) float f32x4;

__device__ __forceinline__ uint32_t hash_lin(int lin) {
    return ((uint32_t)lin * 2654435761u) >> (32 - TBL_BITS);
}

__device__ __forceinline__ void atomPkBf16(uint16_t* p, uint32_t v) {
    asm volatile("global_atomic_pk_add_bf16 %0, %1, off" :: "v"(p), "v"(v) : "memory");
}

// RTNE f32 -> bf16 pair pack
__device__ __forceinline__ uint32_t pk_bf16(float a, float b) {
    uint32_t x = __float_as_uint(a), y = __float_as_uint(b);
    x = (x + 0x7fffu + ((x >> 16) & 1u)) >> 16;
    y = (y + 0x7fffu + ((y >> 16) & 1u)) >> 16;
    return x | (y << 16);
}
__device__ __forceinline__ uint16_t f2bf(float a) {
    uint32_t x = __float_as_uint(a);
    return (uint16_t)((x + 0x7fffu + ((x >> 16) & 1u)) >> 16);
}

__global__ void k_init(int* keys, int* counter,
                       const float2* __restrict__ feat2, uint32_t* featb,
                       const float* __restrict__ W1, uint16_t* w1t,
                       const float* __restrict__ W2, uint16_t* w2t) {
    int i = blockIdx.x * blockDim.x + threadIdx.x;
    int stride = gridDim.x * blockDim.x;
    for (int j = i; j < TBL_SIZE; j += stride) keys[j] = -1;
    for (int j = i; j < N_VOX * IC / 2; j += stride) {
        float2 f = feat2[j];
        featb[j] = pk_bf16(f.x, f.y);
    }
    // W1 [kv][c][o] f32 -> w1t [kv][o][c] bf16
    for (int j = i; j < NKV * IC * OC; j += stride) {
        int kv = j >> 11, c = (j >> 6) & 31, o = j & 63;
        w1t[(kv << 11) + (o << 5) + c] = f2bf(W1[j]);
    }
    // W2 [kv][o][c] f32 -> w2t [kv][c][o] bf16
    for (int j = i; j < NKV * OC * IC; j += stride) {
        int kv = j >> 11, o = (j >> 5) & 63, c = j & 31;
        w2t[(kv << 11) + (c << 6) + o] = f2bf(W2[j]);
    }
    if (i == 0) *counter = 0;
}

__global__ void k_build(const int* __restrict__ coors, int* keys, int* rows) {
    int v = blockIdx.x * blockDim.x + threadIdx.x;
    if (v >= N_VOX) return;
    int b = coors[v * 4 + 0];
    int z = coors[v * 4 + 1];
    int y = coors[v * 4 + 2];
    int x = coors[v * 4 + 3];
#pragma unroll
    for (int kv = 0; kv < NKV; ++kv) {
        int oz = kv / 9, oy = (kv / 3) % 3, ox = kv % 3;
        int az = z + 1 - oz, ay = y + 1 - oy, ax = x + 1 - ox;
        int slot = -1;
        bool valid = (az >= 0) && !(az & 1) && ((az >> 1) < DZ) &&
                     (ay >= 0) && !(ay & 1) && ((ay >> 1) < HY) &&
                     (ax >= 0) && !(ax & 1) && ((ax >> 1) < WX);
        if (valid) {
            int lin = ((b * DZ + (az >> 1)) * HY + (ay >> 1)) * WX + (ax >> 1);
            uint32_t h = hash_lin(lin);
            for (;;) {
                int k = atomicCAS(&keys[h], -1, lin);
                if (k == -1 || k == lin) { slot = (int)h; break; }
                h = (h + 1) & TBL_MASK;
            }
        }
        rows[kv * N_VOX + v] = slot;
    }
}

// Block-aggregated compaction (1 atomic/block) + fused zeroing of the block's
// contiguous claimed row range [base, base+total). Grid row = 128 B bf16.
__global__ __launch_bounds__(256) void k_assign(const int* __restrict__ keys,
                                                int* __restrict__ vals,
                                                int* counter,
                                                float4* __restrict__ grid4) {
    const int t = threadIdx.x;
    const int s0 = blockIdx.x * 2048 + t * 8;
    const int4 a = ((const int4*)(keys + s0))[0];
    const int4 b = ((const int4*)(keys + s0))[1];
    int k[8] = {a.x, a.y, a.z, a.w, b.x, b.y, b.z, b.w};
    int c = 0;
#pragma unroll
    for (int i = 0; i < 8; ++i) c += (k[i] != -1);

    __shared__ int sc[256];
    __shared__ int base;
    sc[t] = c;
    __syncthreads();
#pragma unroll
    for (int d = 1; d < 256; d <<= 1) {
        int y = (t >= d) ? sc[t - d] : 0;
        __syncthreads();
        sc[t] += y;
        __syncthreads();
    }
    if (t == 255) base = atomicAdd(counter, sc[255]);
    __syncthreads();
    const int total = sc[255];
    int r = base + sc[t] - c;  // exclusive prefix
#pragma unroll
    for (int i = 0; i < 8; ++i) {
        if (k[i] != -1) { vals[s0 + i] = (r < MAXROWS) ? r : -1; ++r; }
    }
    int zs = min(base, MAXROWS), ze = min(base + total, MAXROWS);
    float4 zz = {0.f, 0.f, 0.f, 0.f};
    for (int i = zs * 8 + t; i < ze * 8; i += 256) grid4[i] = zz;
}

__global__ void k_rows_fix(int* rows, const int* __restrict__ vals) {
    int i = blockIdx.x * blockDim.x + threadIdx.x;
    if (i >= NKV * N_VOX) return;
    int s = rows[i];
    rows[i] = (s >= 0) ? vals[s] : -1;
}

// Scatter, v-major, D-TRANSPOSED MFMA. Wave owns 32 voxels; kv strided by 2
// across blockIdx.y. A-operand = W1^T frag (m=channel), B-operand = feat frag
// (n=voxel). D: col(lane&15)=voxel, row(lg*4+rg)=channel -> lane-local pk pack,
// no shfl. feat frags loaded once (kv-invariant).
__global__ __launch_bounds__(256) void k_scatter_v(
    const uint16_t* __restrict__ featb, const uint16_t* __restrict__ w1t,
    const int* __restrict__ rows, uint16_t* gridb) {
    const int wid = threadIdx.x >> 6;
    const int lane = threadIdx.x & 63;
    const int v0 = (blockIdx.x * 4 + wid) * 32;
    if (v0 >= N_VOX) return;
    const int ks = blockIdx.y;  // 0 or 1
    const int lg = lane >> 4;
    const int li = lane & 15;

    short8 a[2];  // feat frags (B-operand): lane li = voxel, k = lg*8..+8
#pragma unroll
    for (int mt = 0; mt < 2; ++mt)
        a[mt] = *(const short8*)(featb + (size_t)(v0 + mt * 16 + li) * IC + lg * 8);

    for (int kv = ks; kv < NKV; kv += 2) {
        const int* rkv = rows + kv * N_VOX;
        const uint16_t* w1k = w1t + (kv << 11);
        short8 b[4];  // W1^T frags (A-operand): lane li = out-channel, k = c
#pragma unroll
        for (int nt = 0; nt < 4; ++nt)
            b[nt] = *(const short8*)(w1k + (nt * 16 + li) * IC + lg * 8);
#pragma unroll
        for (int mt = 0; mt < 2; ++mt) {
            const int r = rkv[v0 + mt * 16 + li];  // per-lane (voxel = li)
            uint16_t* rowp = gridb + (size_t)(r < 0 ? 0 : r) * OC + lg * 4;
#pragma unroll
            for (int nt = 0; nt < 4; ++nt) {
                f32x4 d = {0.f, 0.f, 0.f, 0.f};
                d = __builtin_amdgcn_mfma_f32_16x16x32_bf16(b[nt], a[mt], d, 0, 0, 0);
                if (r >= 0) {
                    atomPkBf16(rowp + nt * 16 + 0, pk_bf16(d[0], d[1]));
                    atomPkBf16(rowp + nt * 16 + 2, pk_bf16(d[2], d[3]));
                }
            }
        }
    }
}

// Gather, v-major MFMA (R6, unchanged). Wave owns 32 voxels; loops 27 kv;
// masked A-loads of grid rows + W2^T B-frags; f32 accum; one plain store.
__global__ __launch_bounds__(256) void k_gather_v(
    const uint16_t* __restrict__ gridb, const uint16_t* __restrict__ w2t,
    const int* __restrict__ rows, float* __restrict__ out) {
    const int wid = threadIdx.x >> 6;
    const int lane = threadIdx.x & 63;
    const int v0 = (blockIdx.x * 4 + wid) * 32;
    if (v0 >= N_VOX) return;
    const int lg = lane >> 4;
    const int li = lane & 15;

    f32x4 acc[2][2] = {{{0.f, 0.f, 0.f, 0.f}, {0.f, 0.f, 0.f, 0.f}},
                       {{0.f, 0.f, 0.f, 0.f}, {0.f, 0.f, 0.f, 0.f}}};

    for (int kv = 0; kv < NKV; ++kv) {
        const int* rkv = rows + kv * N_VOX;
        const uint16_t* w2k = w2t + ((size_t)kv << 11);
        short8 b[2][2];  // [ntile][khalf]
#pragma unroll
        for (int nt = 0; nt < 2; ++nt)
#pragma unroll
            for (int kh = 0; kh < 2; ++kh)
                b[nt][kh] = *(const short8*)(w2k + (nt * 16 + li) * 64 +
                                             kh * 32 + lg * 8);
#pragma unroll
        for (int mt = 0; mt < 2; ++mt) {
            const int v = v0 + mt * 16 + li;
            const int r = rkv[v];
            short8 a0 = {0, 0, 0, 0, 0, 0, 0, 0};
            short8 a1 = {0, 0, 0, 0, 0, 0, 0, 0};
            if (r >= 0) {
                const uint16_t* gr = gridb + (size_t)r * OC;
                a0 = *(const short8*)(gr + lg * 8);        // k = 0..31
                a1 = *(const short8*)(gr + 32 + lg * 8);   // k = 32..63
            }
            acc[mt][0] = __builtin_amdgcn_mfma_f32_16x16x32_bf16(a0, b[0][0], acc[mt][0], 0, 0, 0);
            acc[mt][0] = __builtin_amdgcn_mfma_f32_16x16x32_bf16(a1, b[0][1], acc[mt][0], 0, 0, 0);
            acc[mt][1] = __builtin_amdgcn_mfma_f32_16x16x32_bf16(a0, b[1][0], acc[mt][1], 0, 0, 0);
            acc[mt][1] = __builtin_amdgcn_mfma_f32_16x16x32_bf16(a1, b[1][1], acc[mt][1], 0, 0, 0);
        }
    }
#pragma unroll
    for (int mt = 0; mt < 2; ++mt)
#pragma unroll
        for (int nt = 0; nt < 2; ++nt)
#pragma unroll
            for (int rg = 0; rg < 4; ++rg) {
                const int v = v0 + mt * 16 + lg * 4 + rg;
                out[(size_t)v * IC + nt * 16 + li] = acc[mt][nt][rg];
            }
}

extern "C" void kernel_launch(void* const* d_in, const int* in_sizes, int n_in,
                              void* d_out, int out_size, void* d_ws, size_t ws_size,
                              hipStream_t stream) {
    const float* feat = (const float*)d_in[0];
    const int* coors = (const int*)d_in[1];
    const float* W1 = (const float*)d_in[2];
    const float* W2 = (const float*)d_in[3];
    float* out = (float*)d_out;

    if (ws_size < WS_NEEDED) return;  // loud failure: out stays poisoned

    char* ws = (char*)d_ws;
    int* keys = (int*)(ws + OFF_KEYS);
    int* vals = (int*)(ws + OFF_VALS);
    int* counter = (int*)(ws + OFF_CNT);
    int* rows = (int*)(ws + OFF_ROWS);
    uint32_t* featb = (uint32_t*)(ws + OFF_FEATB);
    uint16_t* w2t = (uint16_t*)(ws + OFF_W2T);
    uint16_t* w1t = (uint16_t*)(ws + OFF_W1T);
    uint16_t* gridb = (uint16_t*)(ws + OFF_GRID);

    k_init<<<dim3(4096), dim3(256), 0, stream>>>(keys, counter,
                                                 (const float2*)feat, featb,
                                                 W1, w1t, W2, w2t);
    k_build<<<dim3((N_VOX + 255) / 256), dim3(256), 0, stream>>>(coors, keys, rows);
    k_assign<<<dim3(TBL_SIZE / 2048), dim3(256), 0, stream>>>(keys, vals, counter,
                                                              (float4*)gridb);
    k_rows_fix<<<dim3((NKV * N_VOX + 255) / 256), dim3(256), 0, stream>>>(rows, vals);

    const int nblk = (N_VOX + 127) / 128;  // 4 waves/block, 32 vox/wave
    k_scatter_v<<<dim3(nblk, 2), dim3(256), 0, stream>>>((const uint16_t*)featb,
                                                         w1t, rows, gridb);
    k_gather_v<<<dim3(nblk), dim3(256), 0, stream>>>(gridb, w2t, rows, out);
}

// Round 9
// 306.723 us; speedup vs baseline: 1.0104x; 1.0104x over previous
//
#include <hip/hip_runtime.h>
#include <stdint.h>

// Sparse strided conv: scatter (features@W1 -> grid) + gather (grid@W2 -> out).
// R9: scatter keeps R8's D-transposed MFMA (lane-local pk pack, no shfl) but
//     splits work across blockIdx.y by CHANNEL HALF, not kv: ks block writes
//     channels [32ks,32ks+32) = one distinct 64B line per grid row -> no
//     double-dirty of L2 lines (R8's kv-split doubled WRITE_SIZE 50->100MB).
//     Full 27-kv loop per wave preserves R7's write locality; 7504 waves = 92%.

#define N_VOX 120000
#define IC 32
#define OC 64
#define NKV 27
#define DZ 21
#define HY 200
#define WX 176
#define TBL_BITS 20
#define TBL_SIZE (1 << TBL_BITS)
#define TBL_MASK (TBL_SIZE - 1)
#define MAXROWS 480000

// ws layout (bytes)
#define OFF_KEYS 0                 // 4 MB
#define OFF_VALS 4194304           // 4 MB
#define OFF_CNT 8388608            // 256 B
#define OFF_ROWS 8388864           // 27*120000*4 = 12,960,000
#define OFF_FEATB 21348864         // 120000*32*2 = 7,680,000
#define OFF_W2T 29028864           // 27*32*64*2 = 110,592
#define OFF_W1T 29139456           // 27*64*32*2 = 110,592
#define OFF_GRID 29250048          // MAXROWS*64*2 = 61,440,000
#define WS_NEEDED (OFF_GRID + (size_t)MAXROWS * OC * 2)

typedef __attribute__((ext_vector_type(8))) short short8;
typedef __attribute__((ext_vector_type(4))) float f32x4;

__device__ __forceinline__ uint32_t hash_lin(int lin) {
    return ((uint32_t)lin * 2654435761u) >> (32 - TBL_BITS);
}

__device__ __forceinline__ void atomPkBf16(uint16_t* p, uint32_t v) {
    asm volatile("global_atomic_pk_add_bf16 %0, %1, off" :: "v"(p), "v"(v) : "memory");
}

// RTNE f32 -> bf16 pair pack
__device__ __forceinline__ uint32_t pk_bf16(float a, float b) {
    uint32_t x = __float_as_uint(a), y = __float_as_uint(b);
    x = (x + 0x7fffu + ((x >> 16) & 1u)) >> 16;
    y = (y + 0x7fffu + ((y >> 16) & 1u)) >> 16;
    return x | (y << 16);
}
__device__ __forceinline__ uint16_t f2bf(float a) {
    uint32_t x = __float_as_uint(a);
    return (uint16_t)((x + 0x7fffu + ((x >> 16) & 1u)) >> 16);
}

__global__ void k_init(int* keys, int* counter,
                       const float2* __restrict__ feat2, uint32_t* featb,
                       const float* __restrict__ W1, uint16_t* w1t,
                       const float* __restrict__ W2, uint16_t* w2t) {
    int i = blockIdx.x * blockDim.x + threadIdx.x;
    int stride = gridDim.x * blockDim.x;
    for (int j = i; j < TBL_SIZE; j += stride) keys[j] = -1;
    for (int j = i; j < N_VOX * IC / 2; j += stride) {
        float2 f = feat2[j];
        featb[j] = pk_bf16(f.x, f.y);
    }
    // W1 [kv][c][o] f32 -> w1t [kv][o][c] bf16
    for (int j = i; j < NKV * IC * OC; j += stride) {
        int kv = j >> 11, c = (j >> 6) & 31, o = j & 63;
        w1t[(kv << 11) + (o << 5) + c] = f2bf(W1[j]);
    }
    // W2 [kv][o][c] f32 -> w2t [kv][c][o] bf16
    for (int j = i; j < NKV * OC * IC; j += stride) {
        int kv = j >> 11, o = (j >> 5) & 63, c = j & 31;
        w2t[(kv << 11) + (c << 6) + o] = f2bf(W2[j]);
    }
    if (i == 0) *counter = 0;
}

__global__ void k_build(const int* __restrict__ coors, int* keys, int* rows) {
    int v = blockIdx.x * blockDim.x + threadIdx.x;
    if (v >= N_VOX) return;
    int b = coors[v * 4 + 0];
    int z = coors[v * 4 + 1];
    int y = coors[v * 4 + 2];
    int x = coors[v * 4 + 3];
#pragma unroll
    for (int kv = 0; kv < NKV; ++kv) {
        int oz = kv / 9, oy = (kv / 3) % 3, ox = kv % 3;
        int az = z + 1 - oz, ay = y + 1 - oy, ax = x + 1 - ox;
        int slot = -1;
        bool valid = (az >= 0) && !(az & 1) && ((az >> 1) < DZ) &&
                     (ay >= 0) && !(ay & 1) && ((ay >> 1) < HY) &&
                     (ax >= 0) && !(ax & 1) && ((ax >> 1) < WX);
        if (valid) {
            int lin = ((b * DZ + (az >> 1)) * HY + (ay >> 1)) * WX + (ax >> 1);
            uint32_t h = hash_lin(lin);
            for (;;) {
                int k = atomicCAS(&keys[h], -1, lin);
                if (k == -1 || k == lin) { slot = (int)h; break; }
                h = (h + 1) & TBL_MASK;
            }
        }
        rows[kv * N_VOX + v] = slot;
    }
}

// Block-aggregated compaction (1 atomic/block) + fused zeroing of the block's
// contiguous claimed row range [base, base+total). Grid row = 128 B bf16.
__global__ __launch_bounds__(256) void k_assign(const int* __restrict__ keys,
                                                int* __restrict__ vals,
                                                int* counter,
                                                float4* __restrict__ grid4) {
    const int t = threadIdx.x;
    const int s0 = blockIdx.x * 2048 + t * 8;
    const int4 a = ((const int4*)(keys + s0))[0];
    const int4 b = ((const int4*)(keys + s0))[1];
    int k[8] = {a.x, a.y, a.z, a.w, b.x, b.y, b.z, b.w};
    int c = 0;
#pragma unroll
    for (int i = 0; i < 8; ++i) c += (k[i] != -1);

    __shared__ int sc[256];
    __shared__ int base;
    sc[t] = c;
    __syncthreads();
#pragma unroll
    for (int d = 1; d < 256; d <<= 1) {
        int y = (t >= d) ? sc[t - d] : 0;
        __syncthreads();
        sc[t] += y;
        __syncthreads();
    }
    if (t == 255) base = atomicAdd(counter, sc[255]);
    __syncthreads();
    const int total = sc[255];
    int r = base + sc[t] - c;  // exclusive prefix
#pragma unroll
    for (int i = 0; i < 8; ++i) {
        if (k[i] != -1) { vals[s0 + i] = (r < MAXROWS) ? r : -1; ++r; }
    }
    int zs = min(base, MAXROWS), ze = min(base + total, MAXROWS);
    float4 zz = {0.f, 0.f, 0.f, 0.f};
    for (int i = zs * 8 + t; i < ze * 8; i += 256) grid4[i] = zz;
}

__global__ void k_rows_fix(int* rows, const int* __restrict__ vals) {
    int i = blockIdx.x * blockDim.x + threadIdx.x;
    if (i >= NKV * N_VOX) return;
    int s = rows[i];
    rows[i] = (s >= 0) ? vals[s] : -1;
}

// Scatter, v-major, D-transposed MFMA, CHANNEL-split. Wave owns 32 voxels,
// loops all 27 kv; block ks handles output channels [32ks, 32ks+32) (one
// distinct 64B L2 line per grid row). A-operand = W1^T frag (m=channel),
// B-operand = feat frag (n=voxel). D: col(li)=voxel, row(lg*4+rg)=channel.
__global__ __launch_bounds__(256) void k_scatter_v(
    const uint16_t* __restrict__ featb, const uint16_t* __restrict__ w1t,
    const int* __restrict__ rows, uint16_t* gridb) {
    const int wid = threadIdx.x >> 6;
    const int lane = threadIdx.x & 63;
    const int v0 = (blockIdx.x * 4 + wid) * 32;
    if (v0 >= N_VOX) return;
    const int ks = blockIdx.y;  // channel half: tiles {2ks, 2ks+1}
    const int lg = lane >> 4;
    const int li = lane & 15;

    short8 a[2];  // feat frags (B-operand): lane li = voxel, k = lg*8..+8
#pragma unroll
    for (int mt = 0; mt < 2; ++mt)
        a[mt] = *(const short8*)(featb + (size_t)(v0 + mt * 16 + li) * IC + lg * 8);

    for (int kv = 0; kv < NKV; ++kv) {
        const int* rkv = rows + kv * N_VOX;
        const uint16_t* w1k = w1t + (kv << 11);
        short8 b[2];  // W1^T frags (A-operand), tiles 2ks+nt
#pragma unroll
        for (int nt = 0; nt < 2; ++nt)
            b[nt] = *(const short8*)(w1k + ((ks * 2 + nt) * 16 + li) * IC + lg * 8);
#pragma unroll
        for (int mt = 0; mt < 2; ++mt) {
            const int r = rkv[v0 + mt * 16 + li];  // per-lane (voxel = li)
            uint16_t* rowp = gridb + (size_t)(r < 0 ? 0 : r) * OC + lg * 4;
#pragma unroll
            for (int nt = 0; nt < 2; ++nt) {
                f32x4 d = {0.f, 0.f, 0.f, 0.f};
                d = __builtin_amdgcn_mfma_f32_16x16x32_bf16(b[nt], a[mt], d, 0, 0, 0);
                if (r >= 0) {
                    const int cb = (ks * 2 + nt) * 16;
                    atomPkBf16(rowp + cb + 0, pk_bf16(d[0], d[1]));
                    atomPkBf16(rowp + cb + 2, pk_bf16(d[2], d[3]));
                }
            }
        }
    }
}

// Gather, v-major MFMA (R6, unchanged). Wave owns 32 voxels; loops 27 kv;
// masked A-loads of grid rows + W2^T B-frags; f32 accum; one plain store.
__global__ __launch_bounds__(256) void k_gather_v(
    const uint16_t* __restrict__ gridb, const uint16_t* __restrict__ w2t,
    const int* __restrict__ rows, float* __restrict__ out) {
    const int wid = threadIdx.x >> 6;
    const int lane = threadIdx.x & 63;
    const int v0 = (blockIdx.x * 4 + wid) * 32;
    if (v0 >= N_VOX) return;
    const int lg = lane >> 4;
    const int li = lane & 15;

    f32x4 acc[2][2] = {{{0.f, 0.f, 0.f, 0.f}, {0.f, 0.f, 0.f, 0.f}},
                       {{0.f, 0.f, 0.f, 0.f}, {0.f, 0.f, 0.f, 0.f}}};

    for (int kv = 0; kv < NKV; ++kv) {
        const int* rkv = rows + kv * N_VOX;
        const uint16_t* w2k = w2t + ((size_t)kv << 11);
        short8 b[2][2];  // [ntile][khalf]
#pragma unroll
        for (int nt = 0; nt < 2; ++nt)
#pragma unroll
            for (int kh = 0; kh < 2; ++kh)
                b[nt][kh] = *(const short8*)(w2k + (nt * 16 + li) * 64 +
                                             kh * 32 + lg * 8);
#pragma unroll
        for (int mt = 0; mt < 2; ++mt) {
            const int v = v0 + mt * 16 + li;
            const int r = rkv[v];
            short8 a0 = {0, 0, 0, 0, 0, 0, 0, 0};
            short8 a1 = {0, 0, 0, 0, 0, 0, 0, 0};
            if (r >= 0) {
                const uint16_t* gr = gridb + (size_t)r * OC;
                a0 = *(const short8*)(gr + lg * 8);        // k = 0..31
                a1 = *(const short8*)(gr + 32 + lg * 8);   // k = 32..63
            }
            acc[mt][0] = __builtin_amdgcn_mfma_f32_16x16x32_bf16(a0, b[0][0], acc[mt][0], 0, 0, 0);
            acc[mt][0] = __builtin_amdgcn_mfma_f32_16x16x32_bf16(a1, b[0][1], acc[mt][0], 0, 0, 0);
            acc[mt][1] = __builtin_amdgcn_mfma_f32_16x16x32_bf16(a0, b[1][0], acc[mt][1], 0, 0, 0);
            acc[mt][1] = __builtin_amdgcn_mfma_f32_16x16x32_bf16(a1, b[1][1], acc[mt][1], 0, 0, 0);
        }
    }
#pragma unroll
    for (int mt = 0; mt < 2; ++mt)
#pragma unroll
        for (int nt = 0; nt < 2; ++nt)
#pragma unroll
            for (int rg = 0; rg < 4; ++rg) {
                const int v = v0 + mt * 16 + lg * 4 + rg;
                out[(size_t)v * IC + nt * 16 + li] = acc[mt][nt][rg];
            }
}

extern "C" void kernel_launch(void* const* d_in, const int* in_sizes, int n_in,
                              void* d_out, int out_size, void* d_ws, size_t ws_size,
                              hipStream_t stream) {
    const float* feat = (const float*)d_in[0];
    const int* coors = (const int*)d_in[1];
    const float* W1 = (const float*)d_in[2];
    const float* W2 = (const float*)d_in[3];
    float* out = (float*)d_out;

    if (ws_size < WS_NEEDED) return;  // loud failure: out stays poisoned

    char* ws = (char*)d_ws;
    int* keys = (int*)(ws + OFF_KEYS);
    int* vals = (int*)(ws + OFF_VALS);
    int* counter = (int*)(ws + OFF_CNT);
    int* rows = (int*)(ws + OFF_ROWS);
    uint32_t* featb = (uint32_t*)(ws + OFF_FEATB);
    uint16_t* w2t = (uint16_t*)(ws + OFF_W2T);
    uint16_t* w1t = (uint16_t*)(ws + OFF_W1T);
    uint16_t* gridb = (uint16_t*)(ws + OFF_GRID);

    k_init<<<dim3(4096), dim3(256), 0, stream>>>(keys, counter,
                                                 (const float2*)feat, featb,
                                                 W1, w1t, W2, w2t);
    k_build<<<dim3((N_VOX + 255) / 256), dim3(256), 0, stream>>>(coors, keys, rows);
    k_assign<<<dim3(TBL_SIZE / 2048), dim3(256), 0, stream>>>(keys, vals, counter,
                                                              (float4*)gridb);
    k_rows_fix<<<dim3((NKV * N_VOX + 255) / 256), dim3(256), 0, stream>>>(rows, vals);

    const int nblk = (N_VOX + 127) / 128;  // 4 waves/block, 32 vox/wave
    k_scatter_v<<<dim3(nblk, 2), dim3(256), 0, stream>>>((const uint16_t*)featb,
                                                         w1t, rows, gridb);
    k_gather_v<<<dim3(nblk), dim3(256), 0, stream>>>(gridb, w2t, rows, out);
}

// Round 10
// 302.286 us; speedup vs baseline: 1.0252x; 1.0147x over previous
//
#include <hip/hip_runtime.h>
#include <stdint.h>

// Sparse strided conv: scatter (features@W1 -> grid) + gather (grid@W2 -> out).
// R10: scatter = D-transposed MFMA (R8) + FULL 64-ch row per wave per kv (R7's
//      write locality; L2 line = 128B = one grid row, so splitting row writes
//      across blocks double-dirties lines -- R8/R9's WRITE_SIZE 2x proved it)
//      + occupancy via 16 vox/wave: 1875 blocks x 4 waves = 7500 waves (92%).

#define N_VOX 120000
#define IC 32
#define OC 64
#define NKV 27
#define DZ 21
#define HY 200
#define WX 176
#define TBL_BITS 20
#define TBL_SIZE (1 << TBL_BITS)
#define TBL_MASK (TBL_SIZE - 1)
#define MAXROWS 480000

// ws layout (bytes)
#define OFF_KEYS 0                 // 4 MB
#define OFF_VALS 4194304           // 4 MB
#define OFF_CNT 8388608            // 256 B
#define OFF_ROWS 8388864           // 27*120000*4 = 12,960,000
#define OFF_FEATB 21348864         // 120000*32*2 = 7,680,000
#define OFF_W2T 29028864           // 27*32*64*2 = 110,592
#define OFF_W1T 29139456           // 27*64*32*2 = 110,592
#define OFF_GRID 29250048          // MAXROWS*64*2 = 61,440,000
#define WS_NEEDED (OFF_GRID + (size_t)MAXROWS * OC * 2)

typedef __attribute__((ext_vector_type(8))) short short8;
typedef __attribute__((ext_vector_type(4))) float f32x4;

__device__ __forceinline__ uint32_t hash_lin(int lin) {
    return ((uint32_t)lin * 2654435761u) >> (32 - TBL_BITS);
}

__device__ __forceinline__ void atomPkBf16(uint16_t* p, uint32_t v) {
    asm volatile("global_atomic_pk_add_bf16 %0, %1, off" :: "v"(p), "v"(v) : "memory");
}

// RTNE f32 -> bf16 pair pack
__device__ __forceinline__ uint32_t pk_bf16(float a, float b) {
    uint32_t x = __float_as_uint(a), y = __float_as_uint(b);
    x = (x + 0x7fffu + ((x >> 16) & 1u)) >> 16;
    y = (y + 0x7fffu + ((y >> 16) & 1u)) >> 16;
    return x | (y << 16);
}
__device__ __forceinline__ uint16_t f2bf(float a) {
    uint32_t x = __float_as_uint(a);
    return (uint16_t)((x + 0x7fffu + ((x >> 16) & 1u)) >> 16);
}

__global__ void k_init(int* keys, int* counter,
                       const float2* __restrict__ feat2, uint32_t* featb,
                       const float* __restrict__ W1, uint16_t* w1t,
                       const float* __restrict__ W2, uint16_t* w2t) {
    int i = blockIdx.x * blockDim.x + threadIdx.x;
    int stride = gridDim.x * blockDim.x;
    for (int j = i; j < TBL_SIZE; j += stride) keys[j] = -1;
    for (int j = i; j < N_VOX * IC / 2; j += stride) {
        float2 f = feat2[j];
        featb[j] = pk_bf16(f.x, f.y);
    }
    // W1 [kv][c][o] f32 -> w1t [kv][o][c] bf16
    for (int j = i; j < NKV * IC * OC; j += stride) {
        int kv = j >> 11, c = (j >> 6) & 31, o = j & 63;
        w1t[(kv << 11) + (o << 5) + c] = f2bf(W1[j]);
    }
    // W2 [kv][o][c] f32 -> w2t [kv][c][o] bf16
    for (int j = i; j < NKV * OC * IC; j += stride) {
        int kv = j >> 11, o = (j >> 5) & 63, c = j & 31;
        w2t[(kv << 11) + (c << 6) + o] = f2bf(W2[j]);
    }
    if (i == 0) *counter = 0;
}

__global__ void k_build(const int* __restrict__ coors, int* keys, int* rows) {
    int v = blockIdx.x * blockDim.x + threadIdx.x;
    if (v >= N_VOX) return;
    int b = coors[v * 4 + 0];
    int z = coors[v * 4 + 1];
    int y = coors[v * 4 + 2];
    int x = coors[v * 4 + 3];
#pragma unroll
    for (int kv = 0; kv < NKV; ++kv) {
        int oz = kv / 9, oy = (kv / 3) % 3, ox = kv % 3;
        int az = z + 1 - oz, ay = y + 1 - oy, ax = x + 1 - ox;
        int slot = -1;
        bool valid = (az >= 0) && !(az & 1) && ((az >> 1) < DZ) &&
                     (ay >= 0) && !(ay & 1) && ((ay >> 1) < HY) &&
                     (ax >= 0) && !(ax & 1) && ((ax >> 1) < WX);
        if (valid) {
            int lin = ((b * DZ + (az >> 1)) * HY + (ay >> 1)) * WX + (ax >> 1);
            uint32_t h = hash_lin(lin);
            for (;;) {
                int k = atomicCAS(&keys[h], -1, lin);
                if (k == -1 || k == lin) { slot = (int)h; break; }
                h = (h + 1) & TBL_MASK;
            }
        }
        rows[kv * N_VOX + v] = slot;
    }
}

// Block-aggregated compaction (1 atomic/block) + fused zeroing of the block's
// contiguous claimed row range [base, base+total). Grid row = 128 B bf16.
__global__ __launch_bounds__(256) void k_assign(const int* __restrict__ keys,
                                                int* __restrict__ vals,
                                                int* counter,
                                                float4* __restrict__ grid4) {
    const int t = threadIdx.x;
    const int s0 = blockIdx.x * 2048 + t * 8;
    const int4 a = ((const int4*)(keys + s0))[0];
    const int4 b = ((const int4*)(keys + s0))[1];
    int k[8] = {a.x, a.y, a.z, a.w, b.x, b.y, b.z, b.w};
    int c = 0;
#pragma unroll
    for (int i = 0; i < 8; ++i) c += (k[i] != -1);

    __shared__ int sc[256];
    __shared__ int base;
    sc[t] = c;
    __syncthreads();
#pragma unroll
    for (int d = 1; d < 256; d <<= 1) {
        int y = (t >= d) ? sc[t - d] : 0;
        __syncthreads();
        sc[t] += y;
        __syncthreads();
    }
    if (t == 255) base = atomicAdd(counter, sc[255]);
    __syncthreads();
    const int total = sc[255];
    int r = base + sc[t] - c;  // exclusive prefix
#pragma unroll
    for (int i = 0; i < 8; ++i) {
        if (k[i] != -1) { vals[s0 + i] = (r < MAXROWS) ? r : -1; ++r; }
    }
    int zs = min(base, MAXROWS), ze = min(base + total, MAXROWS);
    float4 zz = {0.f, 0.f, 0.f, 0.f};
    for (int i = zs * 8 + t; i < ze * 8; i += 256) grid4[i] = zz;
}

__global__ void k_rows_fix(int* rows, const int* __restrict__ vals) {
    int i = blockIdx.x * blockDim.x + threadIdx.x;
    if (i >= NKV * N_VOX) return;
    int s = rows[i];
    rows[i] = (s >= 0) ? vals[s] : -1;
}

// Scatter, v-major, D-transposed MFMA, FULL row per wave. Wave owns 16 voxels
// (li = voxel), loops all 27 kv. A-operand = W1^T frag (m=channel, 4 tiles),
// B-operand = feat frag (n=voxel, kv-invariant, loaded once).
// D: col(li)=voxel, row(lg*4+rg)=channel -> lane (lg,li) holds 4 consecutive
// channels of voxel li -> 2 lane-local pk atomics per nt, 8 per kv; the 64
// lanes cover the entire 64ch x 16vox tile, so each grid row's 128B line is
// written in ONE burst (single dirty epoch).
__global__ __launch_bounds__(256) void k_scatter_v(
    const uint16_t* __restrict__ featb, const uint16_t* __restrict__ w1t,
    const int* __restrict__ rows, uint16_t* gridb) {
    const int wid = threadIdx.x >> 6;
    const int lane = threadIdx.x & 63;
    const int v0 = (blockIdx.x * 4 + wid) * 16;
    if (v0 >= N_VOX) return;
    const int lg = lane >> 4;
    const int li = lane & 15;

    // feat frag (B-operand): lane li = voxel v0+li, k(ch) = lg*8..lg*8+8
    const short8 a = *(const short8*)(featb + (size_t)(v0 + li) * IC + lg * 8);

    for (int kv = 0; kv < NKV; ++kv) {
        const int r = rows[kv * N_VOX + v0 + li];  // per-lane (voxel = li)
        const uint16_t* w1k = w1t + (kv << 11);
        uint16_t* rowp = gridb + (size_t)(r < 0 ? 0 : r) * OC + lg * 4;
#pragma unroll
        for (int nt = 0; nt < 4; ++nt) {
            // W1^T frag (A-operand): lane li = out-channel nt*16+li, k = c
            const short8 b = *(const short8*)(w1k + (nt * 16 + li) * IC + lg * 8);
            f32x4 d = {0.f, 0.f, 0.f, 0.f};
            d = __builtin_amdgcn_mfma_f32_16x16x32_bf16(b, a, d, 0, 0, 0);
            if (r >= 0) {
                atomPkBf16(rowp + nt * 16 + 0, pk_bf16(d[0], d[1]));
                atomPkBf16(rowp + nt * 16 + 2, pk_bf16(d[2], d[3]));
            }
        }
    }
}

// Gather, v-major MFMA (R6, unchanged). Wave owns 32 voxels; loops 27 kv;
// masked A-loads of grid rows + W2^T B-frags; f32 accum; one plain store.
__global__ __launch_bounds__(256) void k_gather_v(
    const uint16_t* __restrict__ gridb, const uint16_t* __restrict__ w2t,
    const int* __restrict__ rows, float* __restrict__ out) {
    const int wid = threadIdx.x >> 6;
    const int lane = threadIdx.x & 63;
    const int v0 = (blockIdx.x * 4 + wid) * 32;
    if (v0 >= N_VOX) return;
    const int lg = lane >> 4;
    const int li = lane & 15;

    f32x4 acc[2][2] = {{{0.f, 0.f, 0.f, 0.f}, {0.f, 0.f, 0.f, 0.f}},
                       {{0.f, 0.f, 0.f, 0.f}, {0.f, 0.f, 0.f, 0.f}}};

    for (int kv = 0; kv < NKV; ++kv) {
        const int* rkv = rows + kv * N_VOX;
        const uint16_t* w2k = w2t + ((size_t)kv << 11);
        short8 b[2][2];  // [ntile][khalf]
#pragma unroll
        for (int nt = 0; nt < 2; ++nt)
#pragma unroll
            for (int kh = 0; kh < 2; ++kh)
                b[nt][kh] = *(const short8*)(w2k + (nt * 16 + li) * 64 +
                                             kh * 32 + lg * 8);
#pragma unroll
        for (int mt = 0; mt < 2; ++mt) {
            const int v = v0 + mt * 16 + li;
            const int r = rkv[v];
            short8 a0 = {0, 0, 0, 0, 0, 0, 0, 0};
            short8 a1 = {0, 0, 0, 0, 0, 0, 0, 0};
            if (r >= 0) {
                const uint16_t* gr = gridb + (size_t)r * OC;
                a0 = *(const short8*)(gr + lg * 8);        // k = 0..31
                a1 = *(const short8*)(gr + 32 + lg * 8);   // k = 32..63
            }
            acc[mt][0] = __builtin_amdgcn_mfma_f32_16x16x32_bf16(a0, b[0][0], acc[mt][0], 0, 0, 0);
            acc[mt][0] = __builtin_amdgcn_mfma_f32_16x16x32_bf16(a1, b[0][1], acc[mt][0], 0, 0, 0);
            acc[mt][1] = __builtin_amdgcn_mfma_f32_16x16x32_bf16(a0, b[1][0], acc[mt][1], 0, 0, 0);
            acc[mt][1] = __builtin_amdgcn_mfma_f32_16x16x32_bf16(a1, b[1][1], acc[mt][1], 0, 0, 0);
        }
    }
#pragma unroll
    for (int mt = 0; mt < 2; ++mt)
#pragma unroll
        for (int nt = 0; nt < 2; ++nt)
#pragma unroll
            for (int rg = 0; rg < 4; ++rg) {
                const int v = v0 + mt * 16 + lg * 4 + rg;
                out[(size_t)v * IC + nt * 16 + li] = acc[mt][nt][rg];
            }
}

extern "C" void kernel_launch(void* const* d_in, const int* in_sizes, int n_in,
                              void* d_out, int out_size, void* d_ws, size_t ws_size,
                              hipStream_t stream) {
    const float* feat = (const float*)d_in[0];
    const int* coors = (const int*)d_in[1];
    const float* W1 = (const float*)d_in[2];
    const float* W2 = (const float*)d_in[3];
    float* out = (float*)d_out;

    if (ws_size < WS_NEEDED) return;  // loud failure: out stays poisoned

    char* ws = (char*)d_ws;
    int* keys = (int*)(ws + OFF_KEYS);
    int* vals = (int*)(ws + OFF_VALS);
    int* counter = (int*)(ws + OFF_CNT);
    int* rows = (int*)(ws + OFF_ROWS);
    uint32_t* featb = (uint32_t*)(ws + OFF_FEATB);
    uint16_t* w2t = (uint16_t*)(ws + OFF_W2T);
    uint16_t* w1t = (uint16_t*)(ws + OFF_W1T);
    uint16_t* gridb = (uint16_t*)(ws + OFF_GRID);

    k_init<<<dim3(4096), dim3(256), 0, stream>>>(keys, counter,
                                                 (const float2*)feat, featb,
                                                 W1, w1t, W2, w2t);
    k_build<<<dim3((N_VOX + 255) / 256), dim3(256), 0, stream>>>(coors, keys, rows);
    k_assign<<<dim3(TBL_SIZE / 2048), dim3(256), 0, stream>>>(keys, vals, counter,
                                                              (float4*)gridb);
    k_rows_fix<<<dim3((NKV * N_VOX + 255) / 256), dim3(256), 0, stream>>>(rows, vals);

    // scatter: 16 vox/wave, 4 waves/block -> 64 vox/block -> 1875 blocks (92%)
    k_scatter_v<<<dim3(N_VOX / 64), dim3(256), 0, stream>>>((const uint16_t*)featb,
                                                            w1t, rows, gridb);
    // gather: 32 vox/wave, 4 waves/block -> 938 blocks
    k_gather_v<<<dim3((N_VOX + 127) / 128), dim3(256), 0, stream>>>(gridb, w2t,
                                                                    rows, out);
}

// Round 11
// 230.062 us; speedup vs baseline: 1.3471x; 1.3139x over previous
//
#include <hip/hip_runtime.h>
#include <stdint.h>

// Sparse strided conv: scatter (features@W1 -> grid) + gather (grid@W2 -> out).
// R11: scatter reverted to R7's PROVEN atomic pattern (non-transposed D:
//      8 lanes x 4B = 32B contiguous per grid row per atomic instruction = one
//      full TCC sector -> WRITE_SIZE 50MB). The D-transposed variants (R8-R10)
//      half-filled sectors (4 lanes, stride 8) -> 2 RMW events/sector -> 100MB
//      and 1.7x time, regardless of occupancy. Occupancy fix kept: 16 vox/wave
//      -> 1875 blocks x 4 waves = 7500 waves (92% of slots; R7 had 46% cap).

#define N_VOX 120000
#define IC 32
#define OC 64
#define NKV 27
#define DZ 21
#define HY 200
#define WX 176
#define TBL_BITS 20
#define TBL_SIZE (1 << TBL_BITS)
#define TBL_MASK (TBL_SIZE - 1)
#define MAXROWS 480000

// ws layout (bytes)
#define OFF_KEYS 0                 // 4 MB
#define OFF_VALS 4194304           // 4 MB
#define OFF_CNT 8388608            // 256 B
#define OFF_ROWS 8388864           // 27*120000*4 = 12,960,000
#define OFF_FEATB 21348864         // 120000*32*2 = 7,680,000
#define OFF_W2T 29028864           // 27*32*64*2 = 110,592
#define OFF_W1T 29139456           // 27*64*32*2 = 110,592
#define OFF_GRID 29250048          // MAXROWS*64*2 = 61,440,000
#define WS_NEEDED (OFF_GRID + (size_t)MAXROWS * OC * 2)

typedef __attribute__((ext_vector_type(8))) short short8;
typedef __attribute__((ext_vector_type(4))) float f32x4;

__device__ __forceinline__ uint32_t hash_lin(int lin) {
    return ((uint32_t)lin * 2654435761u) >> (32 - TBL_BITS);
}

__device__ __forceinline__ void atomPkBf16(uint16_t* p, uint32_t v) {
    asm volatile("global_atomic_pk_add_bf16 %0, %1, off" :: "v"(p), "v"(v) : "memory");
}

// RTNE f32 -> bf16 pair pack
__device__ __forceinline__ uint32_t pk_bf16(float a, float b) {
    uint32_t x = __float_as_uint(a), y = __float_as_uint(b);
    x = (x + 0x7fffu + ((x >> 16) & 1u)) >> 16;
    y = (y + 0x7fffu + ((y >> 16) & 1u)) >> 16;
    return x | (y << 16);
}
__device__ __forceinline__ uint16_t f2bf(float a) {
    uint32_t x = __float_as_uint(a);
    return (uint16_t)((x + 0x7fffu + ((x >> 16) & 1u)) >> 16);
}

__global__ void k_init(int* keys, int* counter,
                       const float2* __restrict__ feat2, uint32_t* featb,
                       const float* __restrict__ W1, uint16_t* w1t,
                       const float* __restrict__ W2, uint16_t* w2t) {
    int i = blockIdx.x * blockDim.x + threadIdx.x;
    int stride = gridDim.x * blockDim.x;
    for (int j = i; j < TBL_SIZE; j += stride) keys[j] = -1;
    for (int j = i; j < N_VOX * IC / 2; j += stride) {
        float2 f = feat2[j];
        featb[j] = pk_bf16(f.x, f.y);
    }
    // W1 [kv][c][o] f32 -> w1t [kv][o][c] bf16
    for (int j = i; j < NKV * IC * OC; j += stride) {
        int kv = j >> 11, c = (j >> 6) & 31, o = j & 63;
        w1t[(kv << 11) + (o << 5) + c] = f2bf(W1[j]);
    }
    // W2 [kv][o][c] f32 -> w2t [kv][c][o] bf16
    for (int j = i; j < NKV * OC * IC; j += stride) {
        int kv = j >> 11, o = (j >> 5) & 63, c = j & 31;
        w2t[(kv << 11) + (c << 6) + o] = f2bf(W2[j]);
    }
    if (i == 0) *counter = 0;
}

__global__ void k_build(const int* __restrict__ coors, int* keys, int* rows) {
    int v = blockIdx.x * blockDim.x + threadIdx.x;
    if (v >= N_VOX) return;
    int b = coors[v * 4 + 0];
    int z = coors[v * 4 + 1];
    int y = coors[v * 4 + 2];
    int x = coors[v * 4 + 3];
#pragma unroll
    for (int kv = 0; kv < NKV; ++kv) {
        int oz = kv / 9, oy = (kv / 3) % 3, ox = kv % 3;
        int az = z + 1 - oz, ay = y + 1 - oy, ax = x + 1 - ox;
        int slot = -1;
        bool valid = (az >= 0) && !(az & 1) && ((az >> 1) < DZ) &&
                     (ay >= 0) && !(ay & 1) && ((ay >> 1) < HY) &&
                     (ax >= 0) && !(ax & 1) && ((ax >> 1) < WX);
        if (valid) {
            int lin = ((b * DZ + (az >> 1)) * HY + (ay >> 1)) * WX + (ax >> 1);
            uint32_t h = hash_lin(lin);
            for (;;) {
                int k = atomicCAS(&keys[h], -1, lin);
                if (k == -1 || k == lin) { slot = (int)h; break; }
                h = (h + 1) & TBL_MASK;
            }
        }
        rows[kv * N_VOX + v] = slot;
    }
}

// Block-aggregated compaction (1 atomic/block) + fused zeroing of the block's
// contiguous claimed row range [base, base+total). Grid row = 128 B bf16.
__global__ __launch_bounds__(256) void k_assign(const int* __restrict__ keys,
                                                int* __restrict__ vals,
                                                int* counter,
                                                float4* __restrict__ grid4) {
    const int t = threadIdx.x;
    const int s0 = blockIdx.x * 2048 + t * 8;
    const int4 a = ((const int4*)(keys + s0))[0];
    const int4 b = ((const int4*)(keys + s0))[1];
    int k[8] = {a.x, a.y, a.z, a.w, b.x, b.y, b.z, b.w};
    int c = 0;
#pragma unroll
    for (int i = 0; i < 8; ++i) c += (k[i] != -1);

    __shared__ int sc[256];
    __shared__ int base;
    sc[t] = c;
    __syncthreads();
#pragma unroll
    for (int d = 1; d < 256; d <<= 1) {
        int y = (t >= d) ? sc[t - d] : 0;
        __syncthreads();
        sc[t] += y;
        __syncthreads();
    }
    if (t == 255) base = atomicAdd(counter, sc[255]);
    __syncthreads();
    const int total = sc[255];
    int r = base + sc[t] - c;  // exclusive prefix
#pragma unroll
    for (int i = 0; i < 8; ++i) {
        if (k[i] != -1) { vals[s0 + i] = (r < MAXROWS) ? r : -1; ++r; }
    }
    int zs = min(base, MAXROWS), ze = min(base + total, MAXROWS);
    float4 zz = {0.f, 0.f, 0.f, 0.f};
    for (int i = zs * 8 + t; i < ze * 8; i += 256) grid4[i] = zz;
}

__global__ void k_rows_fix(int* rows, const int* __restrict__ vals) {
    int i = blockIdx.x * blockDim.x + threadIdx.x;
    if (i >= NKV * N_VOX) return;
    int s = rows[i];
    rows[i] = (s >= 0) ? vals[s] : -1;
}

// Scatter, v-major MFMA, R7 atomic pattern + high occupancy. Wave owns 16
// voxels (A-frag m=voxel, loaded once, kv-invariant). Per kv: 4 W1^T B-frags
// (n=channel), one int4 row-id load, 4 mfma, then per (nt,rg): shfl_xor(1)
// pairs channels (li,li+1) and EVEN lanes issue pk atomics -> per instruction
// each of 4 rows gets 8 lanes x 4B = 32B contiguous (one full sector).
// D: col(li)=channel nt*16+li, row(lg*4+rg)=voxel.
__global__ __launch_bounds__(256) void k_scatter_v(
    const uint16_t* __restrict__ featb, const uint16_t* __restrict__ w1t,
    const int* __restrict__ rows, uint16_t* gridb) {
    const int wid = threadIdx.x >> 6;
    const int lane = threadIdx.x & 63;
    const int v0 = (blockIdx.x * 4 + wid) * 16;
    const int lg = lane >> 4;
    const int li = lane & 15;

    // A-operand (feat): m = voxel v0+li, k = lg*8..+8
    const short8 a = *(const short8*)(featb + (size_t)(v0 + li) * IC + lg * 8);

    for (int kv = 0; kv < NKV; ++kv) {
        const int* rkv = rows + kv * N_VOX;
        const uint16_t* w1k = w1t + (kv << 11);
        short8 b[4];  // B-operand (W1^T): n = channel nt*16+li, k = c
#pragma unroll
        for (int nt = 0; nt < 4; ++nt)
            b[nt] = *(const short8*)(w1k + (nt * 16 + li) * IC + lg * 8);
        const int4 r4 = *(const int4*)(rkv + v0 + lg * 4);
        const int rr[4] = {r4.x, r4.y, r4.z, r4.w};
#pragma unroll
        for (int nt = 0; nt < 4; ++nt) {
            f32x4 d = {0.f, 0.f, 0.f, 0.f};
            d = __builtin_amdgcn_mfma_f32_16x16x32_bf16(a, b[nt], d, 0, 0, 0);
#pragma unroll
            for (int rg = 0; rg < 4; ++rg) {
                float other = __shfl_xor(d[rg], 1, 64);
                if ((li & 1) == 0 && rr[rg] >= 0) {
                    atomPkBf16(gridb + (size_t)rr[rg] * OC + nt * 16 + li,
                               pk_bf16(d[rg], other));
                }
            }
        }
    }
}

// Gather, v-major MFMA (R6, unchanged). Wave owns 32 voxels; loops 27 kv;
// masked A-loads of grid rows + W2^T B-frags; f32 accum; one plain store.
__global__ __launch_bounds__(256) void k_gather_v(
    const uint16_t* __restrict__ gridb, const uint16_t* __restrict__ w2t,
    const int* __restrict__ rows, float* __restrict__ out) {
    const int wid = threadIdx.x >> 6;
    const int lane = threadIdx.x & 63;
    const int v0 = (blockIdx.x * 4 + wid) * 32;
    if (v0 >= N_VOX) return;
    const int lg = lane >> 4;
    const int li = lane & 15;

    f32x4 acc[2][2] = {{{0.f, 0.f, 0.f, 0.f}, {0.f, 0.f, 0.f, 0.f}},
                       {{0.f, 0.f, 0.f, 0.f}, {0.f, 0.f, 0.f, 0.f}}};

    for (int kv = 0; kv < NKV; ++kv) {
        const int* rkv = rows + kv * N_VOX;
        const uint16_t* w2k = w2t + ((size_t)kv << 11);
        short8 b[2][2];  // [ntile][khalf]
#pragma unroll
        for (int nt = 0; nt < 2; ++nt)
#pragma unroll
            for (int kh = 0; kh < 2; ++kh)
                b[nt][kh] = *(const short8*)(w2k + (nt * 16 + li) * 64 +
                                             kh * 32 + lg * 8);
#pragma unroll
        for (int mt = 0; mt < 2; ++mt) {
            const int v = v0 + mt * 16 + li;
            const int r = rkv[v];
            short8 a0 = {0, 0, 0, 0, 0, 0, 0, 0};
            short8 a1 = {0, 0, 0, 0, 0, 0, 0, 0};
            if (r >= 0) {
                const uint16_t* gr = gridb + (size_t)r * OC;
                a0 = *(const short8*)(gr + lg * 8);        // k = 0..31
                a1 = *(const short8*)(gr + 32 + lg * 8);   // k = 32..63
            }
            acc[mt][0] = __builtin_amdgcn_mfma_f32_16x16x32_bf16(a0, b[0][0], acc[mt][0], 0, 0, 0);
            acc[mt][0] = __builtin_amdgcn_mfma_f32_16x16x32_bf16(a1, b[0][1], acc[mt][0], 0, 0, 0);
            acc[mt][1] = __builtin_amdgcn_mfma_f32_16x16x32_bf16(a0, b[1][0], acc[mt][1], 0, 0, 0);
            acc[mt][1] = __builtin_amdgcn_mfma_f32_16x16x32_bf16(a1, b[1][1], acc[mt][1], 0, 0, 0);
        }
    }
#pragma unroll
    for (int mt = 0; mt < 2; ++mt)
#pragma unroll
        for (int nt = 0; nt < 2; ++nt)
#pragma unroll
            for (int rg = 0; rg < 4; ++rg) {
                const int v = v0 + mt * 16 + lg * 4 + rg;
                out[(size_t)v * IC + nt * 16 + li] = acc[mt][nt][rg];
            }
}

extern "C" void kernel_launch(void* const* d_in, const int* in_sizes, int n_in,
                              void* d_out, int out_size, void* d_ws, size_t ws_size,
                              hipStream_t stream) {
    const float* feat = (const float*)d_in[0];
    const int* coors = (const int*)d_in[1];
    const float* W1 = (const float*)d_in[2];
    const float* W2 = (const float*)d_in[3];
    float* out = (float*)d_out;

    if (ws_size < WS_NEEDED) return;  // loud failure: out stays poisoned

    char* ws = (char*)d_ws;
    int* keys = (int*)(ws + OFF_KEYS);
    int* vals = (int*)(ws + OFF_VALS);
    int* counter = (int*)(ws + OFF_CNT);
    int* rows = (int*)(ws + OFF_ROWS);
    uint32_t* featb = (uint32_t*)(ws + OFF_FEATB);
    uint16_t* w2t = (uint16_t*)(ws + OFF_W2T);
    uint16_t* w1t = (uint16_t*)(ws + OFF_W1T);
    uint16_t* gridb = (uint16_t*)(ws + OFF_GRID);

    k_init<<<dim3(4096), dim3(256), 0, stream>>>(keys, counter,
                                                 (const float2*)feat, featb,
                                                 W1, w1t, W2, w2t);
    k_build<<<dim3((N_VOX + 255) / 256), dim3(256), 0, stream>>>(coors, keys, rows);
    k_assign<<<dim3(TBL_SIZE / 2048), dim3(256), 0, stream>>>(keys, vals, counter,
                                                              (float4*)gridb);
    k_rows_fix<<<dim3((NKV * N_VOX + 255) / 256), dim3(256), 0, stream>>>(rows, vals);

    // scatter: 16 vox/wave, 4 waves/block -> 1875 blocks = 7500 waves (92%)
    k_scatter_v<<<dim3(N_VOX / 64), dim3(256), 0, stream>>>((const uint16_t*)featb,
                                                            w1t, rows, gridb);
    // gather: 32 vox/wave, 4 waves/block -> 938 blocks
    k_gather_v<<<dim3((N_VOX + 127) / 128), dim3(256), 0, stream>>>(gridb, w2t,
                                                                    rows, out);
}